// Round 3
// baseline (381.366 us; speedup 1.0000x reference)
//
#include <hip/hip_runtime.h>
#include <math.h>

#define EPSF 1e-20f
static constexpr int N  = 32;
static constexpr int Hh = 192;
static constexpr int Ww = 192;
static constexpr int Bb = 2;
static constexpr int HW = Hh * Ww;            // 36864

// workspace layout (bytes)
static constexpr size_t OFFB_WDFRAG  = 0;          // 9*4*32*8 bf16     = 18432 B
static constexpr size_t OFFB_WPROP   = 36864;      // 32*4 fp32         = 512 B
static constexpr size_t OFFB_WPOW    = 37376;      // 32*8 fp32         = 1024 B
static constexpr size_t OFFB_WFRAG   = 40960;      // 9*16*128*8 bf16   = 294912 B
static constexpr size_t OFFB_CE_BF   = 335872;     // 2*HW*128 bf16     = 18874368 B
static constexpr size_t OFFB_ECE_BF  = OFFB_CE_BF + (size_t)2 * HW * 128 * 2;

static constexpr size_t OUT0_SZ  = (size_t)4 * N * HW;      // 4,718,592
static constexpr size_t EOUT_SZ  = (size_t)Bb * N * 4 * HW; // 9,437,184

typedef short bf16x8 __attribute__((ext_vector_type(8)));
typedef float f32x4  __attribute__((ext_vector_type(4)));

__device__ __forceinline__ float softplusf(float x) { return log1pf(expf(x)); }
__device__ __forceinline__ float sigmf(float x)     { return 1.f / (1.f + expf(-x)); }
__device__ __forceinline__ unsigned short f2bf(float f) {
    unsigned int u = __float_as_uint(f);
    u = (u + 0x7fffu + ((u >> 16) & 1u)) >> 16;   // RNE
    return (unsigned short)u;
}
__device__ __forceinline__ float frcp(float x) { return __builtin_amdgcn_rcpf(x); }
__device__ __forceinline__ float fpow01(float r, float p) {
    return __builtin_amdgcn_exp2f(p * __builtin_amdgcn_logf(r));
}
// packed bf16 elementwise multiply (round-half-up repack; inputs in [0,1])
__device__ __forceinline__ bf16x8 bfmul8(bf16x8 a, bf16x8 b) {
    union U { bf16x8 v; unsigned int u[4]; };
    U ua, ub, r; ua.v = a; ub.v = b;
    #pragma unroll
    for (int i = 0; i < 4; ++i) {
        float alo = __uint_as_float(ua.u[i] << 16);
        float ahi = __uint_as_float(ua.u[i] & 0xffff0000u);
        float blo = __uint_as_float(ub.u[i] << 16);
        float bhi = __uint_as_float(ub.u[i] & 0xffff0000u);
        unsigned int lo = __float_as_uint(alo * blo);
        unsigned int hi = __float_as_uint(ahi * bhi);
        lo = (lo + 0x8000u) >> 16;
        hi = (hi + 0x8000u) & 0xffff0000u;
        r.u[i] = hi | lo;
    }
    return r.v;
}

// direct global -> LDS, 16 bytes per lane (LDS dst must be base + lane*16)
typedef __attribute__((address_space(1))) unsigned int ga_u32;
typedef __attribute__((address_space(3))) unsigned int ls_u32;
__device__ __forceinline__ void gload_lds16(const void* g, void* l) {
    __builtin_amdgcn_global_load_lds((ga_u32*)g, (ls_u32*)l, 16, 0, 0);
}

// ---------------------------------------------------------------- weights ---
__global__ void prep_weights(const float* __restrict__ Wcd, const float* __restrict__ Wsd,
                             const float* __restrict__ Wce, const float* __restrict__ Wse0,
                             const float* __restrict__ Wse1, const float* __restrict__ Wse3,
                             const float* __restrict__ Wdir, const float* __restrict__ Wpow,
                             const float* __restrict__ Wprop, char* __restrict__ wsb)
{
    __shared__ float s_wcd[32][32];
    __shared__ float s_wce[32][32];
    __shared__ float s_wsd[32][9];
    __shared__ float s_wse[32][4][9];
    __shared__ float s_wdir[4][32][4];
    const int tid = threadIdx.x;

    if (tid < 64) {
        int o = tid & 31;
        const float* src = (tid < 32) ? Wcd : Wce;
        float s = 0.f;
        for (int i = 0; i < 32; ++i) s += softplusf(src[o * 32 + i]);
        float inv = 1.f / s;
        for (int i = 0; i < 32; ++i) {
            float v = softplusf(src[o * 32 + i]) * inv;
            if (tid < 32) s_wcd[o][i] = v; else s_wce[o][i] = v;
        }
    }
    if (tid < 32) {
        int i = tid;
        float c0[3], c1[3]; float s = 0.f;
        for (int h = 0; h < 3; ++h) {
            c0[h] = softplusf(Wsd[(i * 3 + h) * 2 + 0]);
            c1[h] = softplusf(Wsd[(i * 3 + h) * 2 + 1]);
            s += 2.f * c0[h] + c1[h];
        }
        float inv = 1.f / s;
        for (int h = 0; h < 3; ++h) {
            s_wsd[i][h * 3 + 0] = c0[h] * inv;
            s_wsd[i][h * 3 + 1] = c1[h] * inv;
            s_wsd[i][h * 3 + 2] = c0[h] * inv;
        }
    }
    if (tid < 128) {
        int i = tid >> 2, d = tid & 3;
        float v[9];
        for (int h = 0; h < 3; ++h)
            for (int w = 0; w < 3; ++w) {
                float val;
                if (d == 0)      val = softplusf(Wse0[(i * 3 + h) * 3 + w]);
                else if (d == 1) val = softplusf(Wse1[(i * 3 + h) * 2 + (w == 1 ? 1 : 0)]);
                else if (d == 2) val = softplusf(Wse0[(i * 3 + h) * 3 + (2 - w)]);
                else             val = softplusf(Wse3[(i * 3 + h) * 2 + (w == 1 ? 1 : 0)]);
                v[h * 3 + w] = val;
            }
        float s = 0.f;
        for (int k = 0; k < 9; ++k) s += v[k];
        float inv = 1.f / s;
        for (int k = 0; k < 9; ++k) s_wse[i][d][k] = v[k] * inv;
    }
    if (tid < 128) {
        int p = tid >> 5, i = tid & 31;
        const int jmap[4][4] = {{0,1,2,3},{4,5,4,6},{2,1,0,3},{7,8,7,9}};
        float v[4]; float s = 0.f;
        for (int d = 0; d < 4; ++d) { v[d] = softplusf(Wdir[i * 10 + jmap[p][d]]); s += v[d]; }
        float inv = 1.f / s;
        for (int d = 0; d < 4; ++d) s_wdir[p][i][d] = v[d] * inv;
    }
    if (tid < 32) {
        int i = tid;
        float p0 = softplusf(Wpow[i*5+0]), p1 = softplusf(Wpow[i*5+1]), p2 = softplusf(Wpow[i*5+2]);
        float p3 = softplusf(Wpow[i*5+3]), p4 = softplusf(Wpow[i*5+4]);
        float* wp = (float*)(wsb + OFFB_WPOW) + (size_t)i * 8;
        wp[0]=p0; wp[1]=p2; wp[2]=p1; wp[3]=p4;   // s=0 (fwd)
        wp[4]=p1; wp[5]=p3; wp[6]=p0; wp[7]=p4;   // s=1 (bwd)
        float c0 = sigmf(Wprop[i*3+0]), c1 = sigmf(Wprop[i*3+1]), c2 = sigmf(Wprop[i*3+2]);
        float* pr = (float*)(wsb + OFFB_WPROP) + (size_t)i * 4;
        pr[0]=c1; pr[1]=c0; pr[2]=c1; pr[3]=c2;
    }
    __syncthreads();

    const int gtid = (int)blockIdx.x * 256 + tid;
    const int gstr = (int)(gridDim.x * blockDim.x);
    // conv_d weights in A-fragment bf16 layout: wdf[((tap*4+quad)*32+oc)*8+j], ic=quad*8+j
    unsigned short* wdf = (unsigned short*)(wsb + OFFB_WDFRAG);
    for (int g = gtid; g < 9 * 4 * 32; g += gstr) {
        int oc = g & 31, quad = (g >> 5) & 3, tap = g >> 7;
        unsigned int w[4];
        #pragma unroll
        for (int jp = 0; jp < 4; ++jp) {
            int i0 = quad * 8 + jp * 2;
            unsigned short lo = f2bf(s_wcd[oc][i0]     * s_wsd[i0][tap]);
            unsigned short hi = f2bf(s_wcd[oc][i0 + 1] * s_wsd[i0 + 1][tap]);
            w[jp] = (unsigned int)lo | ((unsigned int)hi << 16);
        }
        *(uint4*)(wdf + (size_t)g * 8) = make_uint4(w[0], w[1], w[2], w[3]);
    }
    // e-conv weights, bf16, A-fragment layout: wfrag[((tap*16+qq)*128+oc)*8+j]
    unsigned short* wfrag = (unsigned short*)(wsb + OFFB_WFRAG);
    for (int g = gtid; g < 9 * 16 * 128; g += gstr) {
        int oc = g & 127, qq = (g >> 7) & 15, tap = g >> 11;
        int o = oc >> 2, p = oc & 3;
        unsigned int w[4];
        #pragma unroll
        for (int jp = 0; jp < 4; ++jp) {
            int ic0 = qq * 8 + jp * 2;
            int i0 = ic0 >> 2, d0 = ic0 & 3;
            int i1 = (ic0 + 1) >> 2, d1 = (ic0 + 1) & 3;
            unsigned short lo = f2bf(s_wce[o][i0] * s_wdir[p][i0][d0] * s_wse[i0][d0][tap]);
            unsigned short hi = f2bf(s_wce[o][i1] * s_wdir[p][i1][d1] * s_wse[i1][d1][tap]);
            w[jp] = (unsigned int)lo | ((unsigned int)hi << 16);
        }
        *(uint4*)(wfrag + (size_t)g * 8) = make_uint4(w[0], w[1], w[2], w[3]);
    }
}

// -------------------------------------------------------------- ce/ece in ---
// 4 channels per thread, 16 channels per block -> each block writes a full,
// aligned 128B line of every 256B pixel record (no cross-block partial lines).
// ~96 independent loads/thread for deep MLP; log-domain ratio math (one log
// per neighbor, clamp in log space == clip(r, EPS, 1) linear).
__global__ __launch_bounds__(256, 6) void prep_inputs(
    const float* __restrict__ xin, const float* __restrict__ ce,
    const float* __restrict__ ece, const char* __restrict__ wsb,
    unsigned short* __restrict__ ce_bf, unsigned short* __restrict__ ece_bf)
{
    const int px   = threadIdx.x & 63;
    const int grp  = threadIdx.x >> 6;        // 0..3
    const int x    = (int)blockIdx.x * 64 + px;
    const int y    = (int)blockIdx.y;
    const int zz   = (int)blockIdx.z;         // b*2 + half
    const int b    = zz >> 1;
    const int i0   = (zz & 1) * 16 + grp * 4; // this thread: channels i0..i0+3
    const float* wprop = (const float*)(wsb + OFFB_WPROP);
    const float* wpow  = (const float*)(wsb + OFFB_WPOW);

    const float LEPS = -66.43856f;            // log2(1e-20)
    // neighbor order k: (dy,dx) = (-1,-1),(-1,0),(-1,1),(0,-1),(0,1),(1,-1),(1,0),(1,1)
    const int kdy[8] = {-1,-1,-1, 0, 0, 1, 1, 1};
    const int kdx[8] = {-1, 0, 1,-1, 1,-1, 0, 1};
    const int fwd[4] = {0, 1, 2, 4};          // d: (-1,-1),(-1,0),(-1,1),(0,1)
    const int bwd[4] = {7, 6, 5, 3};

    unsigned int pc[8], pe[8];
    #pragma unroll
    for (int ii = 0; ii < 4; ++ii) {
        const int i = i0 + ii;
        const float* dcd = xin + ((size_t)(b * N + i)) * HW;
        const float* cd  = xin + ((size_t)((Bb + b) * N + i)) * HW;

        float cdv[8], ldv[8];
        #pragma unroll
        for (int k = 0; k < 8; ++k) {
            int yy = y + kdy[k], xx = x + kdx[k];
            bool in = (yy >= 0 && yy < Hh && xx >= 0 && xx < Ww);
            float c  = in ? cd[yy * Ww + xx] : 0.f;
            float dd = in ? dcd[yy * Ww + xx] : 0.f;
            cdv[k] = c;
            float dv = dd * frcp(c + EPSF);                 // OOB: 0
            ldv[k] = __builtin_amdgcn_logf(dv + EPSF);      // log2
        }
        unsigned short cev[4], ecev[4];
        #pragma unroll
        for (int d = 0; d < 4; ++d) {
            float lr  = ldv[fwd[d]] - ldv[bwd[d]];
            float lrf = fmaxf(fminf(lr, 0.f), LEPS);        // == log2(clip(rf,EPS,1))
            float lrb = fmaxf(fminf(-lr, 0.f), LEPS);
            float p0 = wpow[i * 8 + d], p1 = wpow[i * 8 + 4 + d];
            float ef = __builtin_amdgcn_exp2f(p0 * lrf);
            float eb = __builtin_amdgcn_exp2f(p1 * lrb);
            float en = fminf(ef, eb);                       // already in [0,1]
            float cn = cdv[fwd[d]] * cdv[bwd[d]];
            float wp = wprop[i * 4 + d];
            size_t idx = ((size_t)(b * 128 + i * 4 + d)) * HW + (size_t)y * Ww + x;
            cev[d]  = f2bf(ce[idx] * wp + cn * (1.f - wp));
            ecev[d] = f2bf(ece[idx] * wp + en * cn * (1.f - wp));
        }
        pc[ii * 2 + 0] = (unsigned int)cev[0]  | ((unsigned int)cev[1]  << 16);
        pc[ii * 2 + 1] = (unsigned int)cev[2]  | ((unsigned int)cev[3]  << 16);
        pe[ii * 2 + 0] = (unsigned int)ecev[0] | ((unsigned int)ecev[1] << 16);
        pe[ii * 2 + 1] = (unsigned int)ecev[2] | ((unsigned int)ecev[3] << 16);
    }
    // thread writes 32 contiguous bytes; block covers a full 128B half-record
    size_t base = ((size_t)b * HW + (size_t)y * Ww + x) * 128 + (size_t)i0 * 4;  // shorts
    *(uint4*)(ce_bf  + base)     = make_uint4(pc[0], pc[1], pc[2], pc[3]);
    *(uint4*)(ce_bf  + base + 8) = make_uint4(pc[4], pc[5], pc[6], pc[7]);
    *(uint4*)(ece_bf + base)     = make_uint4(pe[0], pe[1], pe[2], pe[3]);
    *(uint4*)(ece_bf + base + 8) = make_uint4(pe[4], pe[5], pe[6], pe[7]);
}

// ------------------------------------------- 128->128 3x3 conv via MFMA -----
// 16x8 px tile, 128 oc per block; per wave: 64oc x 64px (mt=4, nt=4) ->
// B-ds_read reuse 4x. Linear LDS + chunk XOR swizzle (slot = cq^(p&7))
// -> conflict-free ds_read_b128 AND global_load_lds-compatible staging.
__global__ __launch_bounds__(256, 3) void conv_e_mfma(
    const unsigned short* __restrict__ ce_bf, const unsigned short* __restrict__ ece_bf,
    const unsigned short* __restrict__ wfrag,
    float* __restrict__ ce_out, float* __restrict__ ece_out)
{
    const int z = blockIdx.z; const int t = z >> 1; const int b = z & 1;
    const unsigned short* in_bf = (t ? ece_bf : ce_bf) + (size_t)b * HW * 128;
    float* outp = t ? ece_out : ce_out;

    __shared__ unsigned short tile[180 * 128];   // 10 rows x 18 cols halo, 46080 B

    const int tid  = threadIdx.x;
    const int lane = tid & 63;
    const int l16  = lane & 15;
    const int quad = lane >> 4;
    const int wave = tid >> 6;
    const int ph   = wave >> 1;          // pixel-row half (rows 0-3 / 4-7)
    const int woc  = (wave & 1) * 64;    // oc half
    const int x0 = ((int)blockIdx.x % 12) * 16;
    const int y0 = ((int)blockIdx.x / 12) * 8;

    const bool interior = (x0 >= 16 && x0 <= 160 && y0 >= 8 && y0 <= 176);
    if (interior) {
        #pragma unroll
        for (int it = 0; it < 12; ++it) {
            int idx = it * 256 + tid;
            if (idx < 180 * 16) {
                int p = idx >> 4, slot = idx & 15;
                int hy = p / 18, hx = p - hy * 18;
                int gy = y0 + hy - 1, gx = x0 + hx - 1;
                int csrc = slot ^ (p & 7);
                gload_lds16((const char*)in_bf + ((size_t)(gy * Ww + gx) * 16 + csrc) * 16,
                            (char*)tile + (size_t)idx * 16);
            }
        }
    } else {
        const uint4* gsrc = (const uint4*)in_bf;
        for (int idx = tid; idx < 180 * 16; idx += 256) {
            int p = idx >> 4, slot = idx & 15;
            int hy = p / 18, hx = p - hy * 18;
            int gy = y0 + hy - 1, gx = x0 + hx - 1;
            int csrc = slot ^ (p & 7);
            uint4 v = make_uint4(0u, 0u, 0u, 0u);
            if (gy >= 0 && gy < Hh && gx >= 0 && gx < Ww)
                v = gsrc[(size_t)(gy * Ww + gx) * 16 + csrc];
            *(uint4*)&tile[(size_t)idx * 8] = v;
        }
    }
    __syncthreads();

    f32x4 acc[4][4];   // [mt][nt]
    #pragma unroll
    for (int mt = 0; mt < 4; ++mt)
        #pragma unroll
        for (int nt = 0; nt < 4; ++nt) acc[mt][nt] = (f32x4){0.f, 0.f, 0.f, 0.f};

    for (int tap = 0; tap < 9; ++tap) {
        const int ky = tap / 3, kx = tap - ky * 3;
        #pragma unroll
        for (int q = 0; q < 4; ++q) {
            const int cq = q * 4 + quad;
            const unsigned short* wb = wfrag + (size_t)((tap * 16 + cq) * 128) * 8;
            bf16x8 a[4];
            #pragma unroll
            for (int mt = 0; mt < 4; ++mt)
                a[mt] = *(const bf16x8*)(wb + (size_t)(woc + mt * 16 + l16) * 8);
            #pragma unroll
            for (int nt = 0; nt < 4; ++nt) {
                int px = (ph * 4 + nt + ky) * 18 + l16 + kx;
                bf16x8 bv = *(const bf16x8*)&tile[px * 128 + ((cq ^ (px & 7)) << 3)];
                #pragma unroll
                for (int mt = 0; mt < 4; ++mt)
                    acc[mt][nt] = __builtin_amdgcn_mfma_f32_16x16x32_bf16(a[mt], bv, acc[mt][nt], 0, 0, 0);
            }
        }
    }

    #pragma unroll
    for (int mt = 0; mt < 4; ++mt)
        #pragma unroll
        for (int nt = 0; nt < 4; ++nt) {
            int y = y0 + ph * 4 + nt, x = x0 + l16;
            #pragma unroll
            for (int r = 0; r < 4; ++r) {
                int oc = woc + mt * 16 + quad * 4 + r;
                outp[((size_t)b * 128 + oc) * HW + (size_t)y * Ww + x] = acc[mt][nt][r];
            }
        }
}

// ----------------------- gated 32->32 conv via MFMA (dcd_out & cd_out) ------
__global__ __launch_bounds__(256) void conv_d_mfma(
    const float* __restrict__ xin, const unsigned short* __restrict__ wdfrag,
    const float* __restrict__ ece_out, const float* __restrict__ ce_out,
    float* __restrict__ out0)
{
    const int b = blockIdx.y;
    __shared__ unsigned short xt[2][108 * 40];   // 17280 B
    __shared__ unsigned short Ebf[4 * 64 * 40];  // 20480 B

    const int tid  = threadIdx.x;
    const int lane = tid & 63;
    const int l16  = lane & 15;
    const int quad = lane >> 4;
    const int wave = tid >> 6;
    const int t    = wave >> 1;      // 0: dcd, 1: cd
    const int nh   = wave & 1;       // pixel half
    const int x0 = ((int)blockIdx.x % 12) * 16;
    const int y0 = ((int)blockIdx.x / 12) * 4;

    for (int idx = tid; idx < 2 * 32 * 108; idx += 256) {
        int hp = idx % 108;
        int r = idx / 108; int i = r & 31; int tt = r >> 5;
        int hy = hp / 18, hx = hp - hy * 18;
        int gy = y0 + hy - 1, gx = x0 + hx - 1;
        float v = 0.f;
        if (gy >= 0 && gy < Hh && gx >= 0 && gx < Ww)
            v = xin[((size_t)((tt * Bb + b) * N + i)) * HW + (size_t)gy * Ww + gx];
        xt[tt][hp * 40 + i] = f2bf(v);
    }
    for (int idx = tid; idx < 32 * 64; idx += 256) {
        int px = idx & 15, py = (idx >> 4) & 3, i = idx >> 6;
        size_t gp = (size_t)(y0 + py) * Ww + x0 + px;
        int p = py * 16 + px;
        #pragma unroll
        for (int d = 0; d < 4; ++d) {
            size_t eidx = ((size_t)(b * 128 + i * 4 + d)) * HW + gp;
            float e = fminf(fmaxf(ece_out[eidx] * frcp(ce_out[eidx] + EPSF), EPSF), 1.f);
            Ebf[(d * 64 + p) * 40 + i] = f2bf(e);
        }
    }
    __syncthreads();

    f32x4 acc[2][2];   // [ntile][mtile]
    #pragma unroll
    for (int nt = 0; nt < 2; ++nt)
        #pragma unroll
        for (int mt = 0; mt < 2; ++mt) acc[nt][mt] = (f32x4){0.f, 0.f, 0.f, 0.f};

    const int dmap[9] = {0, 1, 2, 3, 0, 3, 2, 1, 0};   // index 4 unused
    #pragma unroll
    for (int tap = 0; tap < 9; ++tap) {
        const int ky = tap / 3, kx = tap % 3;
        bf16x8 a0 = *(const bf16x8*)(wdfrag + (size_t)(((tap * 4 + quad) * 32) + l16) * 8);
        bf16x8 a1 = *(const bf16x8*)(wdfrag + (size_t)(((tap * 4 + quad) * 32) + 16 + l16) * 8);
        #pragma unroll
        for (int nt = 0; nt < 2; ++nt) {
            int p = nh * 32 + nt * 16 + l16;
            int py = p >> 4, px = p & 15;
            int hp = (py + ky) * 18 + px + kx;
            bf16x8 xv = *(const bf16x8*)&xt[t][hp * 40 + quad * 8];
            bf16x8 g;
            if (tap == 4) g = xv;
            else {
                bf16x8 ev = *(const bf16x8*)&Ebf[(dmap[tap] * 64 + p) * 40 + quad * 8];
                g = bfmul8(xv, ev);
            }
            acc[nt][0] = __builtin_amdgcn_mfma_f32_16x16x32_bf16(a0, g, acc[nt][0], 0, 0, 0);
            acc[nt][1] = __builtin_amdgcn_mfma_f32_16x16x32_bf16(a1, g, acc[nt][1], 0, 0, 0);
        }
    }

    #pragma unroll
    for (int nt = 0; nt < 2; ++nt) {
        int p = nh * 32 + nt * 16 + l16;
        int py = p >> 4, px = p & 15;
        size_t gp = (size_t)(y0 + py) * Ww + x0 + px;
        #pragma unroll
        for (int mt = 0; mt < 2; ++mt)
            #pragma unroll
            for (int r = 0; r < 4; ++r) {
                int oc = mt * 16 + quad * 4 + r;
                out0[((size_t)((t * Bb + b) * N + oc)) * HW + gp] = acc[nt][mt][r];
            }
    }
}

extern "C" void kernel_launch(void* const* d_in, const int* in_sizes, int n_in,
                              void* d_out, int out_size, void* d_ws, size_t ws_size,
                              hipStream_t stream)
{
    const float* x     = (const float*)d_in[0];
    const float* ece   = (const float*)d_in[1];
    const float* ce    = (const float*)d_in[2];
    const float* Wcd   = (const float*)d_in[3];
    const float* Wsd   = (const float*)d_in[4];
    const float* Wce   = (const float*)d_in[5];
    const float* Wse0  = (const float*)d_in[6];
    const float* Wse1  = (const float*)d_in[7];
    const float* Wse3  = (const float*)d_in[8];
    const float* Wdir  = (const float*)d_in[9];
    const float* Wpow  = (const float*)d_in[10];
    const float* Wprop = (const float*)d_in[11];
    float* out = (float*)d_out;
    char* wsb  = (char*)d_ws;

    unsigned short* ce_bf  = (unsigned short*)(wsb + OFFB_CE_BF);
    unsigned short* ece_bf = (unsigned short*)(wsb + OFFB_ECE_BF);
    unsigned short* wfrag  = (unsigned short*)(wsb + OFFB_WFRAG);
    unsigned short* wdfrag = (unsigned short*)(wsb + OFFB_WDFRAG);
    float* out0    = out;
    float* ece_out = out + OUT0_SZ;
    float* ce_out  = out + OUT0_SZ + EOUT_SZ;

    prep_weights<<<8, 256, 0, stream>>>(Wcd, Wsd, Wce, Wse0, Wse1, Wse3, Wdir, Wpow, Wprop, wsb);
    prep_inputs<<<dim3(3, Hh, Bb * 2), 256, 0, stream>>>(x, ce, ece, wsb, ce_bf, ece_bf);
    conv_e_mfma<<<dim3(288, 1, 4), 256, 0, stream>>>(ce_bf, ece_bf, wfrag, ce_out, ece_out);
    conv_d_mfma<<<dim3(576, Bb), 256, 0, stream>>>(x, wdfrag, ece_out, ce_out, out0);
}

// Round 4
// 323.051 us; speedup vs baseline: 1.1805x; 1.1805x over previous
//
#include <hip/hip_runtime.h>
#include <math.h>

#define EPSF 1e-20f
static constexpr int N  = 32;
static constexpr int Hh = 192;
static constexpr int Ww = 192;
static constexpr int Bb = 2;
static constexpr int HW = Hh * Ww;            // 36864

// workspace layout (bytes)
static constexpr size_t OFFB_WDFRAG  = 0;          // 9*4*32*8 bf16     = 18432 B
static constexpr size_t OFFB_WPROP   = 36864;      // 32*4 fp32         = 512 B
static constexpr size_t OFFB_WPOW    = 37376;      // 32*8 fp32         = 1024 B
static constexpr size_t OFFB_WFRAG   = 40960;      // 9*16*128*8 bf16   = 294912 B
static constexpr size_t OFFB_CE_BF   = 335872;     // 2*HW*128 bf16     = 18874368 B
static constexpr size_t OFFB_ECE_BF  = OFFB_CE_BF + (size_t)2 * HW * 128 * 2;

static constexpr size_t OUT0_SZ  = (size_t)4 * N * HW;      // 4,718,592
static constexpr size_t EOUT_SZ  = (size_t)Bb * N * 4 * HW; // 9,437,184

typedef short bf16x8 __attribute__((ext_vector_type(8)));
typedef float f32x4  __attribute__((ext_vector_type(4)));

__device__ __forceinline__ float softplusf(float x) { return log1pf(expf(x)); }
__device__ __forceinline__ float sigmf(float x)     { return 1.f / (1.f + expf(-x)); }
__device__ __forceinline__ unsigned short f2bf(float f) {
    unsigned int u = __float_as_uint(f);
    u = (u + 0x7fffu + ((u >> 16) & 1u)) >> 16;   // RNE
    return (unsigned short)u;
}
__device__ __forceinline__ float frcp(float x) { return __builtin_amdgcn_rcpf(x); }
__device__ __forceinline__ float fpow01(float r, float p) {
    return __builtin_amdgcn_exp2f(p * __builtin_amdgcn_logf(r));
}
// packed bf16 elementwise multiply (round-half-up repack; inputs in [0,1])
__device__ __forceinline__ bf16x8 bfmul8(bf16x8 a, bf16x8 b) {
    union U { bf16x8 v; unsigned int u[4]; };
    U ua, ub, r; ua.v = a; ub.v = b;
    #pragma unroll
    for (int i = 0; i < 4; ++i) {
        float alo = __uint_as_float(ua.u[i] << 16);
        float ahi = __uint_as_float(ua.u[i] & 0xffff0000u);
        float blo = __uint_as_float(ub.u[i] << 16);
        float bhi = __uint_as_float(ub.u[i] & 0xffff0000u);
        unsigned int lo = __float_as_uint(alo * blo);
        unsigned int hi = __float_as_uint(ahi * bhi);
        lo = (lo + 0x8000u) >> 16;
        hi = (hi + 0x8000u) & 0xffff0000u;
        r.u[i] = hi | lo;
    }
    return r.v;
}

// direct global -> LDS, 16 bytes per lane (LDS dst must be base + lane*16)
typedef __attribute__((address_space(1))) unsigned int ga_u32;
typedef __attribute__((address_space(3))) unsigned int ls_u32;
__device__ __forceinline__ void gload_lds16(const void* g, void* l) {
    __builtin_amdgcn_global_load_lds((ga_u32*)g, (ls_u32*)l, 16, 0, 0);
}

// ---------------------------------------------------------------- weights ---
__global__ void prep_weights(const float* __restrict__ Wcd, const float* __restrict__ Wsd,
                             const float* __restrict__ Wce, const float* __restrict__ Wse0,
                             const float* __restrict__ Wse1, const float* __restrict__ Wse3,
                             const float* __restrict__ Wdir, const float* __restrict__ Wpow,
                             const float* __restrict__ Wprop, char* __restrict__ wsb)
{
    __shared__ float s_wcd[32][32];
    __shared__ float s_wce[32][32];
    __shared__ float s_wsd[32][9];
    __shared__ float s_wse[32][4][9];
    __shared__ float s_wdir[4][32][4];
    const int tid = threadIdx.x;

    if (tid < 64) {
        int o = tid & 31;
        const float* src = (tid < 32) ? Wcd : Wce;
        float s = 0.f;
        for (int i = 0; i < 32; ++i) s += softplusf(src[o * 32 + i]);
        float inv = 1.f / s;
        for (int i = 0; i < 32; ++i) {
            float v = softplusf(src[o * 32 + i]) * inv;
            if (tid < 32) s_wcd[o][i] = v; else s_wce[o][i] = v;
        }
    }
    if (tid < 32) {
        int i = tid;
        float c0[3], c1[3]; float s = 0.f;
        for (int h = 0; h < 3; ++h) {
            c0[h] = softplusf(Wsd[(i * 3 + h) * 2 + 0]);
            c1[h] = softplusf(Wsd[(i * 3 + h) * 2 + 1]);
            s += 2.f * c0[h] + c1[h];
        }
        float inv = 1.f / s;
        for (int h = 0; h < 3; ++h) {
            s_wsd[i][h * 3 + 0] = c0[h] * inv;
            s_wsd[i][h * 3 + 1] = c1[h] * inv;
            s_wsd[i][h * 3 + 2] = c0[h] * inv;
        }
    }
    if (tid < 128) {
        int i = tid >> 2, d = tid & 3;
        float v[9];
        for (int h = 0; h < 3; ++h)
            for (int w = 0; w < 3; ++w) {
                float val;
                if (d == 0)      val = softplusf(Wse0[(i * 3 + h) * 3 + w]);
                else if (d == 1) val = softplusf(Wse1[(i * 3 + h) * 2 + (w == 1 ? 1 : 0)]);
                else if (d == 2) val = softplusf(Wse0[(i * 3 + h) * 3 + (2 - w)]);
                else             val = softplusf(Wse3[(i * 3 + h) * 2 + (w == 1 ? 1 : 0)]);
                v[h * 3 + w] = val;
            }
        float s = 0.f;
        for (int k = 0; k < 9; ++k) s += v[k];
        float inv = 1.f / s;
        for (int k = 0; k < 9; ++k) s_wse[i][d][k] = v[k] * inv;
    }
    if (tid < 128) {
        int p = tid >> 5, i = tid & 31;
        const int jmap[4][4] = {{0,1,2,3},{4,5,4,6},{2,1,0,3},{7,8,7,9}};
        float v[4]; float s = 0.f;
        for (int d = 0; d < 4; ++d) { v[d] = softplusf(Wdir[i * 10 + jmap[p][d]]); s += v[d]; }
        float inv = 1.f / s;
        for (int d = 0; d < 4; ++d) s_wdir[p][i][d] = v[d] * inv;
    }
    if (tid < 32) {
        int i = tid;
        float p0 = softplusf(Wpow[i*5+0]), p1 = softplusf(Wpow[i*5+1]), p2 = softplusf(Wpow[i*5+2]);
        float p3 = softplusf(Wpow[i*5+3]), p4 = softplusf(Wpow[i*5+4]);
        float* wp = (float*)(wsb + OFFB_WPOW) + (size_t)i * 8;
        wp[0]=p0; wp[1]=p2; wp[2]=p1; wp[3]=p4;   // s=0 (fwd)
        wp[4]=p1; wp[5]=p3; wp[6]=p0; wp[7]=p4;   // s=1 (bwd)
        float c0 = sigmf(Wprop[i*3+0]), c1 = sigmf(Wprop[i*3+1]), c2 = sigmf(Wprop[i*3+2]);
        float* pr = (float*)(wsb + OFFB_WPROP) + (size_t)i * 4;
        pr[0]=c1; pr[1]=c0; pr[2]=c1; pr[3]=c2;
    }
    __syncthreads();

    const int gtid = (int)blockIdx.x * 256 + tid;
    const int gstr = (int)(gridDim.x * blockDim.x);
    // conv_d weights in A-fragment bf16 layout: wdf[((tap*4+quad)*32+oc)*8+j], ic=quad*8+j
    unsigned short* wdf = (unsigned short*)(wsb + OFFB_WDFRAG);
    for (int g = gtid; g < 9 * 4 * 32; g += gstr) {
        int oc = g & 31, quad = (g >> 5) & 3, tap = g >> 7;
        unsigned int w[4];
        #pragma unroll
        for (int jp = 0; jp < 4; ++jp) {
            int i0 = quad * 8 + jp * 2;
            unsigned short lo = f2bf(s_wcd[oc][i0]     * s_wsd[i0][tap]);
            unsigned short hi = f2bf(s_wcd[oc][i0 + 1] * s_wsd[i0 + 1][tap]);
            w[jp] = (unsigned int)lo | ((unsigned int)hi << 16);
        }
        *(uint4*)(wdf + (size_t)g * 8) = make_uint4(w[0], w[1], w[2], w[3]);
    }
    // e-conv weights, bf16, A-fragment layout: wfrag[((tap*16+qq)*128+oc)*8+j]
    unsigned short* wfrag = (unsigned short*)(wsb + OFFB_WFRAG);
    for (int g = gtid; g < 9 * 16 * 128; g += gstr) {
        int oc = g & 127, qq = (g >> 7) & 15, tap = g >> 11;
        int o = oc >> 2, p = oc & 3;
        unsigned int w[4];
        #pragma unroll
        for (int jp = 0; jp < 4; ++jp) {
            int ic0 = qq * 8 + jp * 2;
            int i0 = ic0 >> 2, d0 = ic0 & 3;
            int i1 = (ic0 + 1) >> 2, d1 = (ic0 + 1) & 3;
            unsigned short lo = f2bf(s_wce[o][i0] * s_wdir[p][i0][d0] * s_wse[i0][d0][tap]);
            unsigned short hi = f2bf(s_wce[o][i1] * s_wdir[p][i1][d1] * s_wse[i1][d1][tap]);
            w[jp] = (unsigned int)lo | ((unsigned int)hi << 16);
        }
        *(uint4*)(wfrag + (size_t)g * 8) = make_uint4(w[0], w[1], w[2], w[3]);
    }
}

// -------------------------------------------------------------- ce/ece in ---
// REVERTED to the measured-best r2 layout: 2 channels/thread, 8 channels/block,
// one uint4 store per array per thread (58.0 us, FETCH 82.9 MB, WRITE 48.5 MB).
// The 4ch/thread + 2-store variant amplified DRAM traffic 2.4x (r3 post-mortem).
__global__ __launch_bounds__(256, 6) void prep_inputs(
    const float* __restrict__ xin, const float* __restrict__ ce,
    const float* __restrict__ ece, const char* __restrict__ wsb,
    unsigned short* __restrict__ ce_bf, unsigned short* __restrict__ ece_bf)
{
    const int px  = threadIdx.x & 63;
    const int grp = threadIdx.x >> 6;        // 0..3
    const int x   = (int)blockIdx.x * 64 + px;
    const int y   = (int)blockIdx.y;
    const int zz  = (int)blockIdx.z;         // b*4 + cb
    const int b   = zz >> 2;
    const int i0  = (zz & 3) * 8 + grp * 2;  // this thread: channels i0, i0+1
    const float* wprop = (const float*)(wsb + OFFB_WPROP);
    const float* wpow  = (const float*)(wsb + OFFB_WPOW);

    const float LEPS = -66.43856f;           // log2(1e-20)
    // neighbor order k: (dy,dx) = (-1,-1),(-1,0),(-1,1),(0,-1),(0,1),(1,-1),(1,0),(1,1)
    const int kdy[8] = {-1,-1,-1, 0, 0, 1, 1, 1};
    const int kdx[8] = {-1, 0, 1,-1, 1,-1, 0, 1};
    const int fwd[4] = {0, 1, 2, 4};         // d: (-1,-1),(-1,0),(-1,1),(0,1)
    const int bwd[4] = {7, 6, 5, 3};

    unsigned int pc[4], pe[4];
    #pragma unroll
    for (int ii = 0; ii < 2; ++ii) {
        const int i = i0 + ii;
        const float* dcd = xin + ((size_t)(b * N + i)) * HW;
        const float* cd  = xin + ((size_t)((Bb + b) * N + i)) * HW;

        float cdv[8], ldv[8];
        #pragma unroll
        for (int k = 0; k < 8; ++k) {
            int yy = y + kdy[k], xx = x + kdx[k];
            bool in = (yy >= 0 && yy < Hh && xx >= 0 && xx < Ww);
            float c  = in ? cd[yy * Ww + xx] : 0.f;
            float dd = in ? dcd[yy * Ww + xx] : 0.f;
            cdv[k] = c;
            float dv = dd * frcp(c + EPSF);                 // OOB: 0
            ldv[k] = __builtin_amdgcn_logf(dv + EPSF);      // log2
        }
        unsigned short cev[4], ecev[4];
        #pragma unroll
        for (int d = 0; d < 4; ++d) {
            float lr  = ldv[fwd[d]] - ldv[bwd[d]];
            float lrf = fmaxf(fminf(lr, 0.f), LEPS);        // == log2(clip(rf,EPS,1))
            float lrb = fmaxf(fminf(-lr, 0.f), LEPS);
            float p0 = wpow[i * 8 + d], p1 = wpow[i * 8 + 4 + d];
            float ef = __builtin_amdgcn_exp2f(p0 * lrf);
            float eb = __builtin_amdgcn_exp2f(p1 * lrb);
            float en = fminf(ef, eb);                       // already in [0,1]
            float cn = cdv[fwd[d]] * cdv[bwd[d]];
            float wp = wprop[i * 4 + d];
            size_t idx = ((size_t)(b * 128 + i * 4 + d)) * HW + (size_t)y * Ww + x;
            cev[d]  = f2bf(ce[idx] * wp + cn * (1.f - wp));
            ecev[d] = f2bf(ece[idx] * wp + en * cn * (1.f - wp));
        }
        pc[ii * 2 + 0] = (unsigned int)cev[0]  | ((unsigned int)cev[1]  << 16);
        pc[ii * 2 + 1] = (unsigned int)cev[2]  | ((unsigned int)cev[3]  << 16);
        pe[ii * 2 + 0] = (unsigned int)ecev[0] | ((unsigned int)ecev[1] << 16);
        pe[ii * 2 + 1] = (unsigned int)ecev[2] | ((unsigned int)ecev[3] << 16);
    }
    size_t base = ((size_t)b * HW + (size_t)y * Ww + x) * 128 + (size_t)i0 * 4;  // shorts
    *(uint4*)(ce_bf  + base) = make_uint4(pc[0], pc[1], pc[2], pc[3]);
    *(uint4*)(ece_bf + base) = make_uint4(pe[0], pe[1], pe[2], pe[3]);
}

// ------------------------------------------- 128->128 3x3 conv via MFMA -----
// 16x8 px tile, 128 oc per block; per wave: 64oc x 64px (mt=4, nt=4) ->
// B-ds_read reuse 4x. Linear LDS + chunk XOR swizzle (slot = cq^(p&7))
// -> conflict-free ds_read_b128 AND global_load_lds-compatible staging.
__global__ __launch_bounds__(256, 3) void conv_e_mfma(
    const unsigned short* __restrict__ ce_bf, const unsigned short* __restrict__ ece_bf,
    const unsigned short* __restrict__ wfrag,
    float* __restrict__ ce_out, float* __restrict__ ece_out)
{
    const int z = blockIdx.z; const int t = z >> 1; const int b = z & 1;
    const unsigned short* in_bf = (t ? ece_bf : ce_bf) + (size_t)b * HW * 128;
    float* outp = t ? ece_out : ce_out;

    __shared__ unsigned short tile[180 * 128];   // 10 rows x 18 cols halo, 46080 B

    const int tid  = threadIdx.x;
    const int lane = tid & 63;
    const int l16  = lane & 15;
    const int quad = lane >> 4;
    const int wave = tid >> 6;
    const int ph   = wave >> 1;          // pixel-row half (rows 0-3 / 4-7)
    const int woc  = (wave & 1) * 64;    // oc half
    const int x0 = ((int)blockIdx.x % 12) * 16;
    const int y0 = ((int)blockIdx.x / 12) * 8;

    const bool interior = (x0 >= 16 && x0 <= 160 && y0 >= 8 && y0 <= 176);
    if (interior) {
        #pragma unroll
        for (int it = 0; it < 12; ++it) {
            int idx = it * 256 + tid;
            if (idx < 180 * 16) {
                int p = idx >> 4, slot = idx & 15;
                int hy = p / 18, hx = p - hy * 18;
                int gy = y0 + hy - 1, gx = x0 + hx - 1;
                int csrc = slot ^ (p & 7);
                gload_lds16((const char*)in_bf + ((size_t)(gy * Ww + gx) * 16 + csrc) * 16,
                            (char*)tile + (size_t)idx * 16);
            }
        }
    } else {
        const uint4* gsrc = (const uint4*)in_bf;
        for (int idx = tid; idx < 180 * 16; idx += 256) {
            int p = idx >> 4, slot = idx & 15;
            int hy = p / 18, hx = p - hy * 18;
            int gy = y0 + hy - 1, gx = x0 + hx - 1;
            int csrc = slot ^ (p & 7);
            uint4 v = make_uint4(0u, 0u, 0u, 0u);
            if (gy >= 0 && gy < Hh && gx >= 0 && gx < Ww)
                v = gsrc[(size_t)(gy * Ww + gx) * 16 + csrc];
            *(uint4*)&tile[(size_t)idx * 8] = v;
        }
    }
    __syncthreads();

    f32x4 acc[4][4];   // [mt][nt]
    #pragma unroll
    for (int mt = 0; mt < 4; ++mt)
        #pragma unroll
        for (int nt = 0; nt < 4; ++nt) acc[mt][nt] = (f32x4){0.f, 0.f, 0.f, 0.f};

    for (int tap = 0; tap < 9; ++tap) {
        const int ky = tap / 3, kx = tap - ky * 3;
        #pragma unroll
        for (int q = 0; q < 4; ++q) {
            const int cq = q * 4 + quad;
            const unsigned short* wb = wfrag + (size_t)((tap * 16 + cq) * 128) * 8;
            bf16x8 a[4];
            #pragma unroll
            for (int mt = 0; mt < 4; ++mt)
                a[mt] = *(const bf16x8*)(wb + (size_t)(woc + mt * 16 + l16) * 8);
            #pragma unroll
            for (int nt = 0; nt < 4; ++nt) {
                int px = (ph * 4 + nt + ky) * 18 + l16 + kx;
                bf16x8 bv = *(const bf16x8*)&tile[px * 128 + ((cq ^ (px & 7)) << 3)];
                #pragma unroll
                for (int mt = 0; mt < 4; ++mt)
                    acc[mt][nt] = __builtin_amdgcn_mfma_f32_16x16x32_bf16(a[mt], bv, acc[mt][nt], 0, 0, 0);
            }
        }
    }

    #pragma unroll
    for (int mt = 0; mt < 4; ++mt)
        #pragma unroll
        for (int nt = 0; nt < 4; ++nt) {
            int y = y0 + ph * 4 + nt, x = x0 + l16;
            #pragma unroll
            for (int r = 0; r < 4; ++r) {
                int oc = woc + mt * 16 + quad * 4 + r;
                outp[((size_t)b * 128 + oc) * HW + (size_t)y * Ww + x] = acc[mt][nt][r];
            }
        }
}

// ----------------------- gated 32->32 conv via MFMA (dcd_out & cd_out) ------
__global__ __launch_bounds__(256) void conv_d_mfma(
    const float* __restrict__ xin, const unsigned short* __restrict__ wdfrag,
    const float* __restrict__ ece_out, const float* __restrict__ ce_out,
    float* __restrict__ out0)
{
    const int b = blockIdx.y;
    __shared__ unsigned short xt[2][108 * 40];   // 17280 B
    __shared__ unsigned short Ebf[4 * 64 * 40];  // 20480 B

    const int tid  = threadIdx.x;
    const int lane = tid & 63;
    const int l16  = lane & 15;
    const int quad = lane >> 4;
    const int wave = tid >> 6;
    const int t    = wave >> 1;      // 0: dcd, 1: cd
    const int nh   = wave & 1;       // pixel half
    const int x0 = ((int)blockIdx.x % 12) * 16;
    const int y0 = ((int)blockIdx.x / 12) * 4;

    for (int idx = tid; idx < 2 * 32 * 108; idx += 256) {
        int hp = idx % 108;
        int r = idx / 108; int i = r & 31; int tt = r >> 5;
        int hy = hp / 18, hx = hp - hy * 18;
        int gy = y0 + hy - 1, gx = x0 + hx - 1;
        float v = 0.f;
        if (gy >= 0 && gy < Hh && gx >= 0 && gx < Ww)
            v = xin[((size_t)((tt * Bb + b) * N + i)) * HW + (size_t)gy * Ww + gx];
        xt[tt][hp * 40 + i] = f2bf(v);
    }
    for (int idx = tid; idx < 32 * 64; idx += 256) {
        int px = idx & 15, py = (idx >> 4) & 3, i = idx >> 6;
        size_t gp = (size_t)(y0 + py) * Ww + x0 + px;
        int p = py * 16 + px;
        #pragma unroll
        for (int d = 0; d < 4; ++d) {
            size_t eidx = ((size_t)(b * 128 + i * 4 + d)) * HW + gp;
            float e = fminf(fmaxf(ece_out[eidx] * frcp(ce_out[eidx] + EPSF), EPSF), 1.f);
            Ebf[(d * 64 + p) * 40 + i] = f2bf(e);
        }
    }
    __syncthreads();

    f32x4 acc[2][2];   // [ntile][mtile]
    #pragma unroll
    for (int nt = 0; nt < 2; ++nt)
        #pragma unroll
        for (int mt = 0; mt < 2; ++mt) acc[nt][mt] = (f32x4){0.f, 0.f, 0.f, 0.f};

    const int dmap[9] = {0, 1, 2, 3, 0, 3, 2, 1, 0};   // index 4 unused
    #pragma unroll
    for (int tap = 0; tap < 9; ++tap) {
        const int ky = tap / 3, kx = tap % 3;
        bf16x8 a0 = *(const bf16x8*)(wdfrag + (size_t)(((tap * 4 + quad) * 32) + l16) * 8);
        bf16x8 a1 = *(const bf16x8*)(wdfrag + (size_t)(((tap * 4 + quad) * 32) + 16 + l16) * 8);
        #pragma unroll
        for (int nt = 0; nt < 2; ++nt) {
            int p = nh * 32 + nt * 16 + l16;
            int py = p >> 4, px = p & 15;
            int hp = (py + ky) * 18 + px + kx;
            bf16x8 xv = *(const bf16x8*)&xt[t][hp * 40 + quad * 8];
            bf16x8 g;
            if (tap == 4) g = xv;
            else {
                bf16x8 ev = *(const bf16x8*)&Ebf[(dmap[tap] * 64 + p) * 40 + quad * 8];
                g = bfmul8(xv, ev);
            }
            acc[nt][0] = __builtin_amdgcn_mfma_f32_16x16x32_bf16(a0, g, acc[nt][0], 0, 0, 0);
            acc[nt][1] = __builtin_amdgcn_mfma_f32_16x16x32_bf16(a1, g, acc[nt][1], 0, 0, 0);
        }
    }

    #pragma unroll
    for (int nt = 0; nt < 2; ++nt) {
        int p = nh * 32 + nt * 16 + l16;
        int py = p >> 4, px = p & 15;
        size_t gp = (size_t)(y0 + py) * Ww + x0 + px;
        #pragma unroll
        for (int mt = 0; mt < 2; ++mt)
            #pragma unroll
            for (int r = 0; r < 4; ++r) {
                int oc = mt * 16 + quad * 4 + r;
                out0[((size_t)((t * Bb + b) * N + oc)) * HW + gp] = acc[nt][mt][r];
            }
    }
}

extern "C" void kernel_launch(void* const* d_in, const int* in_sizes, int n_in,
                              void* d_out, int out_size, void* d_ws, size_t ws_size,
                              hipStream_t stream)
{
    const float* x     = (const float*)d_in[0];
    const float* ece   = (const float*)d_in[1];
    const float* ce    = (const float*)d_in[2];
    const float* Wcd   = (const float*)d_in[3];
    const float* Wsd   = (const float*)d_in[4];
    const float* Wce   = (const float*)d_in[5];
    const float* Wse0  = (const float*)d_in[6];
    const float* Wse1  = (const float*)d_in[7];
    const float* Wse3  = (const float*)d_in[8];
    const float* Wdir  = (const float*)d_in[9];
    const float* Wpow  = (const float*)d_in[10];
    const float* Wprop = (const float*)d_in[11];
    float* out = (float*)d_out;
    char* wsb  = (char*)d_ws;

    unsigned short* ce_bf  = (unsigned short*)(wsb + OFFB_CE_BF);
    unsigned short* ece_bf = (unsigned short*)(wsb + OFFB_ECE_BF);
    unsigned short* wfrag  = (unsigned short*)(wsb + OFFB_WFRAG);
    unsigned short* wdfrag = (unsigned short*)(wsb + OFFB_WDFRAG);
    float* out0    = out;
    float* ece_out = out + OUT0_SZ;
    float* ce_out  = out + OUT0_SZ + EOUT_SZ;

    prep_weights<<<32, 256, 0, stream>>>(Wcd, Wsd, Wce, Wse0, Wse1, Wse3, Wdir, Wpow, Wprop, wsb);
    prep_inputs<<<dim3(3, Hh, Bb * 4), 256, 0, stream>>>(x, ce, ece, wsb, ce_bf, ece_bf);
    conv_e_mfma<<<dim3(288, 1, 4), 256, 0, stream>>>(ce_bf, ece_bf, wfrag, ce_out, ece_out);
    conv_d_mfma<<<dim3(576, Bb), 256, 0, stream>>>(x, wdfrag, ece_out, ce_out, out0);
}